// Round 2
// baseline (375.394 us; speedup 1.0000x reference)
//
#include <hip/hip_runtime.h>
#include <math.h>

// Problem constants (fixed shapes per setup_inputs):
//   x_in: (32768, 543, 3) fp32; num_frames=16384; segments=4; input_shape=(16384,240)
//   x (reduced): (32768, 80, 3); out = [5 stat feats of 480] + [16384*240 resized] = 3934560 fp32
#define T_FRAMES   32768
#define N_LM       543
#define FRAME      1629          // 543*3 floats per frame
#define FPB        16            // frames per block
#define NBLOCKS    (T_FRAMES / FPB)   // 2048
#define TILES      4             // 4-frame tiles per block (FPB/4)
#define TILE_F4    1629          // float4 per 4-frame tile (6516 floats, 16B-divisible)
#define OUT_B_OFF  2400          // 5 feats * 480
#define ACC_FLOATS 1920          // 4 segments * (240 sum + 240 sumsq)

__constant__ int   c_astart[10] = {0, 40, 80, 140, 200, 260, 320, 370, 420, 480};
__constant__ int   c_alen[10]   = {40, 40, 60, 60, 60, 60, 50, 50, 60, 63};

__global__ void zero_acc_kernel(float* __restrict__ acc) {
    int i = blockIdx.x * 256 + threadIdx.x;
    if (i < ACC_FLOATS) acc[i] = 0.0f;
}

// One block = 16 consecutive frames = 8 output rows, all inside one segment.
// Pipeline: prefetch tile g+1 into registers, compute tile g from LDS,
// barrier, write regs->LDS, barrier.  2 barriers/tile.
// Roles: leader lane (j8==0) of 8-lane group g8<30 emits mean-feature g8
// (accumulating into lsum/lsq); thread t in [30,240) emits point-landmark
// feature t (accumulating into ssum/ssq).  A thread can hold BOTH roles --
// the accumulators MUST stay separate (round-1 bug: shared ssum cross-
// contaminated features g8 and t on leader lanes with t>=30).
__global__ __launch_bounds__(256, 6) void featgen_main(
    const float* __restrict__ xin, float* __restrict__ out, float* __restrict__ acc)
{
    __shared__ float rows[4 * FRAME];   // 26064 B: one 4-frame tile

    const int t = threadIdx.x;
    const int b = blockIdx.x;
    const float* src = xin + (size_t)b * (FPB * FRAME);

    // Role: 8 lanes per (l,c) range-mean; groups of 8 stay inside a wave.
    const int g8 = t >> 3;          // 0..31, active if < 30
    const int j8 = t & 7;
    int a_s = 0, a_n = 0, a_c = 0;
    float a_inv = 0.0f;
    if (g8 < 30) {
        int l = g8 / 3; a_c = g8 - 3 * l;
        a_s = c_astart[l]; a_n = c_alen[l];
        a_inv = 1.0f / (float)a_n;
    }

    float ssum = 0.0f, ssq = 0.0f;   // point-landmark feature t (30<=t<240)
    float lsum = 0.0f, lsq = 0.0f;   // mean feature g8 (leader lanes only)

    float4 pre[7];

    // ---- prologue: stage tile 0 ----
    {
        const float4* s4 = (const float4*)src;
        #pragma unroll
        for (int i = 0; i < 7; ++i) {
            int idx = t + i * 256;
            if (idx < TILE_F4) pre[i] = s4[idx];
        }
        float4* d4 = (float4*)rows;
        #pragma unroll
        for (int i = 0; i < 7; ++i) {
            int idx = t + i * 256;
            if (idx < TILE_F4) d4[idx] = pre[i];
        }
    }
    __syncthreads();

    for (int grp = 0; grp < TILES; ++grp) {
        // ---- issue next tile's loads early (latency hides under compute) ----
        if (grp < TILES - 1) {
            const float4* s4 = (const float4*)(src + (size_t)(grp + 1) * (4 * FRAME));
            #pragma unroll
            for (int i = 0; i < 7; ++i) {
                int idx = t + i * 256;
                if (idx < TILE_F4) pre[i] = s4[idx];
            }
        }

        const size_t row0 = (size_t)b * (FPB / 2) + (size_t)grp * 2;

        // ---- range means: 8-lane cooperative reduce; leader emits directly ----
        if (g8 < 30) {
            float v[4];
            #pragma unroll
            for (int f = 0; f < 4; ++f) {
                const float* row = rows + f * FRAME;
                float s = 0.0f;
                for (int j = j8; j < a_n; j += 8) s += row[(a_s + j) * 3 + a_c];
                s += __shfl_xor(s, 1, 8);
                s += __shfl_xor(s, 2, 8);
                s += __shfl_xor(s, 4, 8);
                v[f] = s * a_inv;
            }
            if (j8 == 0) {
                out[OUT_B_OFF + row0 * 240 + g8]       = 0.5f * (v[0] + v[1]);
                out[OUT_B_OFF + (row0 + 1) * 240 + g8] = 0.5f * (v[2] + v[3]);
                lsum += v[0] + v[1] + v[2] + v[3];
                lsq  += v[0]*v[0] + v[1]*v[1] + v[2]*v[2] + v[3]*v[3];
            }
        }

        // ---- point landmarks: thread t owns feature t (30..239) ----
        if (t >= 30 && t < 240) {
            float v0 = rows[0 * FRAME + t + 1374];
            float v1 = rows[1 * FRAME + t + 1374];
            float v2 = rows[2 * FRAME + t + 1374];
            float v3 = rows[3 * FRAME + t + 1374];
            out[OUT_B_OFF + row0 * 240 + t]       = 0.5f * (v0 + v1);
            out[OUT_B_OFF + (row0 + 1) * 240 + t] = 0.5f * (v2 + v3);
            ssum += v0 + v1 + v2 + v3;
            ssq  += v0*v0 + v1*v1 + v2*v2 + v3*v3;
        }

        __syncthreads();   // everyone done reading rows

        if (grp < TILES - 1) {
            float4* d4 = (float4*)rows;
            #pragma unroll
            for (int i = 0; i < 7; ++i) {
                int idx = t + i * 256;
                if (idx < TILE_F4) d4[idx] = pre[i];
            }
            __syncthreads();   // rows ready for next tile
        }
    }

    // ---- per-block stats into segment accumulators (roles kept separate) ----
    const int seg = b >> 9;   // 512 blocks per segment
    if (g8 < 30 && j8 == 0) {
        atomicAdd(&acc[seg * 480 + g8],       lsum);
        atomicAdd(&acc[seg * 480 + 240 + g8], lsq);
    }
    if (t >= 30 && t < 240) {
        atomicAdd(&acc[seg * 480 + t],       ssum);
        atomicAdd(&acc[seg * 480 + 240 + t], ssq);
    }
}

// 5 blocks: f=0..3 segment feats, f=4 full-range feat.
__global__ __launch_bounds__(256) void finalize_stats(
    const float* __restrict__ acc, float* __restrict__ out)
{
    const int f = blockIdx.x;
    const int t = threadIdx.x;
    if (t >= 240) return;
    float s, q, n;
    if (f < 4) {
        s = acc[f * 480 + t];
        q = acc[f * 480 + 240 + t];
        n = 8192.0f;
    } else {
        s = acc[t]       + acc[480 + t]  + acc[960 + t]  + acc[1440 + t];
        q = acc[240 + t] + acc[720 + t]  + acc[1200 + t] + acc[1680 + t];
        n = 32768.0f;
    }
    float mean = s / n;
    float var  = q / n - mean * mean;
    var = var < 0.0f ? 0.0f : var;
    out[f * 480 + t]       = mean;
    out[f * 480 + 240 + t] = sqrtf(var);
}

extern "C" void kernel_launch(void* const* d_in, const int* in_sizes, int n_in,
                              void* d_out, int out_size, void* d_ws, size_t ws_size,
                              hipStream_t stream) {
    (void)in_sizes; (void)n_in; (void)out_size; (void)ws_size;
    const float* xin = (const float*)d_in[0];
    float* out = (float*)d_out;
    float* acc = (float*)d_ws;

    zero_acc_kernel<<<8, 256, 0, stream>>>(acc);
    featgen_main<<<NBLOCKS, 256, 0, stream>>>(xin, out, acc);
    finalize_stats<<<5, 256, 0, stream>>>(acc, out);
}

// Round 3
// 311.089 us; speedup vs baseline: 1.2067x; 1.2067x over previous
//
#include <hip/hip_runtime.h>
#include <math.h>
#include <stdint.h>

// Problem constants (fixed shapes per setup_inputs):
//   x_in: (32768, 543, 3) fp32; num_frames=16384; segments=4; input_shape=(16384,240)
//   x (reduced): (32768, 80, 3); out = [5 stat feats of 480] + [16384*240 resized] = 3934560 fp32
#define T_FRAMES   32768
#define N_LM       543
#define FRAME      1629          // 543*3 floats per frame
#define FPB        32            // frames per block
#define NBLOCKS    (T_FRAMES / FPB)   // 1024
#define TILES      8             // 4-frame tiles per block (FPB/4)
#define TILE_BYTES 26064         // 4*FRAME*4 bytes per tile (16B-divisible)
#define CHUNKS     26            // ceil(26064 / 1024): 25 full 1KB chunks + 464B tail
#define BUF_FLOATS 6660          // 4*FRAME + 144 pad floats (absorbs chunk-25 slack)
#define OUT_B_OFF  2400          // 5 feats * 480
#define ACC_FLOATS 1920          // 4 segments * (240 sum + 240 sumsq)

__constant__ int   c_astart[10] = {0, 40, 80, 140, 200, 260, 320, 370, 420, 480};
__constant__ int   c_alen[10]   = {40, 40, 60, 60, 60, 60, 50, 50, 60, 63};

typedef const __attribute__((address_space(1))) uint32_t* gas_ptr;
typedef __attribute__((address_space(3)))       uint32_t* las_ptr;

__global__ void zero_acc_kernel(float* __restrict__ acc) {
    int i = blockIdx.x * 256 + threadIdx.x;
    if (i < ACC_FLOATS) acc[i] = 0.0f;
}

// Async DMA one 4-frame tile (26064 B) global -> LDS, no VGPR staging.
// Chunk c (1024 B = 64 lanes x 16 B) handled by wave c&3; LDS dest is
// wave-uniform base + lane*16 (linear, as global_load_lds requires).
// Completion is tracked by the issuing wave's vmcnt; the compiler drains
// vmcnt(0) before the next s_barrier, which is exactly the sync we need.
__device__ __forceinline__ void stage_tile(const float* __restrict__ gsrc,
                                           float* lbase, int w, int lane)
{
    #pragma unroll
    for (int i = 0; i < 7; ++i) {
        int c = w + 4 * i;
        if (c < CHUNKS) {
            int off = c * 1024 + lane * 16;       // byte offset in tile
            if (off < TILE_BYTES) {               // masks tail lanes of chunk 25
                __builtin_amdgcn_global_load_lds(
                    (gas_ptr)((const uint8_t*)gsrc + off),
                    (las_ptr)((uint8_t*)lbase + c * 1024),
                    16, 0, 0);
            }
        }
    }
}

// One block = 32 consecutive frames = 16 output rows, all inside one segment.
// Double-buffered LDS pipeline: while computing tile g from buf[g&1], tile
// g+1 streams into buf[(g+1)&1] via global_load_lds. ONE barrier per tile:
// it both publishes the staged tile and protects the buffer being reused.
// Roles: leader lane (j8==0) of 8-lane group g8<30 emits mean-feature g8
// (accumulating into lsum/lsq); thread t in [30,240) emits point-landmark
// feature t (ssum/ssq). Accumulators MUST stay separate (round-1 bug).
__global__ __launch_bounds__(256) void featgen_main(
    const float* __restrict__ xin, float* __restrict__ out, float* __restrict__ acc)
{
    __shared__ __align__(16) float buf[2][BUF_FLOATS];   // 53280 B -> 3 blocks/CU

    const int t    = threadIdx.x;
    const int b    = blockIdx.x;
    const int w    = t >> 6;
    const int lane = t & 63;
    const float* src = xin + (size_t)b * (FPB * FRAME);

    // Role: 8 lanes per (l,c) range-mean; groups of 8 stay inside a wave.
    const int g8 = t >> 3;          // 0..31, active if < 30
    const int j8 = t & 7;
    int a_s = 0, a_n = 0, a_c = 0;
    float a_inv = 0.0f;
    if (g8 < 30) {
        int l = g8 / 3; a_c = g8 - 3 * l;
        a_s = c_astart[l]; a_n = c_alen[l];
        a_inv = 1.0f / (float)a_n;
    }

    float ssum = 0.0f, ssq = 0.0f;   // point-landmark feature t (30<=t<240)
    float lsum = 0.0f, lsq = 0.0f;   // mean feature g8 (leader lanes only)

    // ---- prologue: DMA tile 0 ----
    stage_tile(src, buf[0], w, lane);
    __syncthreads();   // compiler-inserted vmcnt(0) drain makes tile 0 visible

    for (int grp = 0; grp < TILES; ++grp) {
        const float* rows = buf[grp & 1];

        // ---- issue next tile's DMA; latency hides under this tile's compute ----
        if (grp < TILES - 1)
            stage_tile(src + (size_t)(grp + 1) * (4 * FRAME), buf[(grp + 1) & 1], w, lane);

        const size_t row0 = (size_t)b * (FPB / 2) + (size_t)grp * 2;

        // ---- range means: 8-lane cooperative reduce; leader emits directly ----
        if (g8 < 30) {
            float v[4];
            #pragma unroll
            for (int f = 0; f < 4; ++f) {
                const float* row = rows + f * FRAME;
                float s = 0.0f;
                for (int j = j8; j < a_n; j += 8) s += row[(a_s + j) * 3 + a_c];
                s += __shfl_xor(s, 1, 8);
                s += __shfl_xor(s, 2, 8);
                s += __shfl_xor(s, 4, 8);
                v[f] = s * a_inv;
            }
            if (j8 == 0) {
                out[OUT_B_OFF + row0 * 240 + g8]       = 0.5f * (v[0] + v[1]);
                out[OUT_B_OFF + (row0 + 1) * 240 + g8] = 0.5f * (v[2] + v[3]);
                lsum += v[0] + v[1] + v[2] + v[3];
                lsq  += v[0]*v[0] + v[1]*v[1] + v[2]*v[2] + v[3]*v[3];
            }
        }

        // ---- point landmarks: thread t owns feature t (30..239) ----
        if (t >= 30 && t < 240) {
            float v0 = rows[0 * FRAME + t + 1374];
            float v1 = rows[1 * FRAME + t + 1374];
            float v2 = rows[2 * FRAME + t + 1374];
            float v3 = rows[3 * FRAME + t + 1374];
            out[OUT_B_OFF + row0 * 240 + t]       = 0.5f * (v0 + v1);
            out[OUT_B_OFF + (row0 + 1) * 240 + t] = 0.5f * (v2 + v3);
            ssum += v0 + v1 + v2 + v3;
            ssq  += v0*v0 + v1*v1 + v2*v2 + v3*v3;
        }

        // One barrier: publishes tile g+1 (vmcnt drained before s_barrier)
        // AND guarantees all reads of buf[g&1] finished before grp+1 reuses it.
        __syncthreads();
    }

    // ---- per-block stats into segment accumulators (roles kept separate) ----
    const int seg = b >> 8;   // 256 blocks per segment
    if (g8 < 30 && j8 == 0) {
        atomicAdd(&acc[seg * 480 + g8],       lsum);
        atomicAdd(&acc[seg * 480 + 240 + g8], lsq);
    }
    if (t >= 30 && t < 240) {
        atomicAdd(&acc[seg * 480 + t],       ssum);
        atomicAdd(&acc[seg * 480 + 240 + t], ssq);
    }
}

// 5 blocks: f=0..3 segment feats, f=4 full-range feat.
__global__ __launch_bounds__(256) void finalize_stats(
    const float* __restrict__ acc, float* __restrict__ out)
{
    const int f = blockIdx.x;
    const int t = threadIdx.x;
    if (t >= 240) return;
    float s, q, n;
    if (f < 4) {
        s = acc[f * 480 + t];
        q = acc[f * 480 + 240 + t];
        n = 8192.0f;
    } else {
        s = acc[t]       + acc[480 + t]  + acc[960 + t]  + acc[1440 + t];
        q = acc[240 + t] + acc[720 + t]  + acc[1200 + t] + acc[1680 + t];
        n = 32768.0f;
    }
    float mean = s / n;
    float var  = q / n - mean * mean;
    var = var < 0.0f ? 0.0f : var;
    out[f * 480 + t]       = mean;
    out[f * 480 + 240 + t] = sqrtf(var);
}

extern "C" void kernel_launch(void* const* d_in, const int* in_sizes, int n_in,
                              void* d_out, int out_size, void* d_ws, size_t ws_size,
                              hipStream_t stream) {
    (void)in_sizes; (void)n_in; (void)out_size; (void)ws_size;
    const float* xin = (const float*)d_in[0];
    float* out = (float*)d_out;
    float* acc = (float*)d_ws;

    zero_acc_kernel<<<8, 256, 0, stream>>>(acc);
    featgen_main<<<NBLOCKS, 256, 0, stream>>>(xin, out, acc);
    finalize_stats<<<5, 256, 0, stream>>>(acc, out);
}